// Round 13
// baseline (308.539 us; speedup 1.0000x reference)
//
#include <hip/hip_runtime.h>
#include <hip/hip_bf16.h>

// GAT: 3x (GATConv + Linear skip), N=50000, E=800000(+N self loops)
// R13: col stored as ushort (N<65536) — halves bucket's random-write RFO
//     traffic and agg4/agg2 col reads; agg4 adds an 8-edge mid-loop for
//     MLP in the common deg~17 case; bucket loads both ei streams up front.

#define NEG_SLOPE 0.2f
#define SC_CHUNK 4096
#define CAP 64

typedef __attribute__((ext_vector_type(8))) short short8;
typedef __attribute__((ext_vector_type(4))) float floatx4;

static __device__ __forceinline__ float leaky(float x) {
    return x > 0.f ? x : NEG_SLOPE * x;
}

static __device__ __forceinline__ unsigned short f2bf(float f) {
    unsigned int u = __float_as_uint(f);
    u = (u + 0x7fffu + ((u >> 16) & 1u)) >> 16;  // RNE
    return (unsigned short)u;
}

static __device__ __forceinline__ unsigned int pack_bf2(float lo, float hi) {
    return (unsigned int)f2bf(lo) | ((unsigned int)f2bf(hi) << 16);
}

static __device__ __forceinline__ float bflo(unsigned int u) {
    return __uint_as_float(u << 16);
}
static __device__ __forceinline__ float bfhi(unsigned int u) {
    return __uint_as_float(u & 0xffff0000u);
}

static __device__ __forceinline__ short8 frag_from_f32(const float* p) {
    float4 f0 = ((const float4*)p)[0];
    float4 f1 = ((const float4*)p)[1];
    short8 r;
    r[0] = (short)f2bf(f0.x); r[1] = (short)f2bf(f0.y);
    r[2] = (short)f2bf(f0.z); r[3] = (short)f2bf(f0.w);
    r[4] = (short)f2bf(f1.x); r[5] = (short)f2bf(f1.y);
    r[6] = (short)f2bf(f1.z); r[7] = (short)f2bf(f1.w);
    return r;
}

// ---------------- bucket build + weight converts (merged) ----------------
__global__ __launch_bounds__(256) void k_bucket(
    const int* __restrict__ ei, int E, int N, int rs,
    int* __restrict__ cnt, unsigned short* __restrict__ col,
    const float* __restrict__ W0, unsigned short* __restrict__ T0,
    const float* __restrict__ W1, unsigned short* __restrict__ T1,
    const float* __restrict__ W2, unsigned short* __restrict__ T2,
    const float* __restrict__ W3, unsigned short* __restrict__ T3,
    const float* __restrict__ c2W, const float* __restrict__ l2W,
    unsigned short* __restrict__ WT5) {
    if (blockIdx.y == gridDim.y - 1) {
        int tid = blockIdx.x * 256 + threadIdx.x;  // 0..2047
        for (int j = tid; j < 65536; j += 2048) {
            int wsel = j >> 14, t = j & 16383;
            int n = t >> 7, k = t & 127;
            const float* W = (wsel == 0) ? W0 : (wsel == 1) ? W1 : (wsel == 2) ? W2 : W3;
            unsigned short* T = (wsel == 0) ? T0 : (wsel == 1) ? T1 : (wsel == 2) ? T2 : T3;
            T[n * 128 + k] = f2bf(W[k * 128 + n]);
        }
        {
            int n = tid >> 7, k = tid & 127;
            float v = 0.f;
            if (n < 12) v = c2W[k * 12 + n];
            else if (n < 14) v = l2W[k * 2 + (n - 12)];
            WT5[n * 128 + k] = f2bf(v);
        }
        return;
    }
    int lo = blockIdx.x * rs, hi = lo + rs;
    int base = blockIdx.y * SC_CHUNK;
    int ET = E + N;
#pragma unroll 4
    for (int o = threadIdx.x; o < SC_CHUNK; o += 256) {
        int e = base + o;
        if (e >= ET) break;
        int d, s;
        if (e < E) { d = ei[E + e]; s = ei[e]; }   // two independent streams
        else       { d = e - E;     s = d; }
        if (d < lo || d >= hi) continue;
        int pos = atomicAdd(&cnt[d], 1);
        if (pos < CAP) col[(d << 6) + pos] = (unsigned short)s;  // guard
    }
}

// ---------------- MFMA GEMM: C = A @ W^T(stored as WT[n][k]) -------------
// W staged in LDS (padded). Block = 128 rows; wave w computes tiles w, w+4.
__global__ __launch_bounds__(256) void k_gemm_mfma(
    const float* __restrict__ x0,            // [M,128] fp32 or null
    const unsigned short* __restrict__ Ab,   // [Mpad,128] bf16
    const unsigned short* __restrict__ W1T,  // [128,128] bf16, n-major
    unsigned int* __restrict__ XWb,          // [M,64] packed (c, c+64)
    const float* __restrict__ a_s, const float* __restrict__ a_d,
    float4* __restrict__ ALS4, float4* __restrict__ ALD4,
    const unsigned short* __restrict__ W2T,
    const float* __restrict__ b2,
    unsigned short* __restrict__ Hsb,        // [M,128] bf16 skip
    int M) {
    __shared__ short8 Wl[128 * 17];          // 34 KB, padded
    int which = blockIdx.y;
    const short8* W8 = (const short8*)(which ? W2T : W1T);

    for (int u = threadIdx.x; u < 2048; u += 256)
        Wl[(u >> 4) * 17 + (u & 15)] = W8[u];

    int w = threadIdx.x >> 6, lane = threadIdx.x & 63;
    int m = lane & 15, q = lane >> 4;
    const short8* A8 = (const short8*)Ab;

    short8 af[2][4];
    int rt0 = blockIdx.x * 8 + w;            // tile indices rt0, rt0+4
#pragma unroll
    for (int t = 0; t < 2; t++) {
        int arow = (rt0 + t * 4) * 16 + m;
        int lrow = (arow < M) ? arow : (M - 1);
#pragma unroll
        for (int ks = 0; ks < 4; ks++) {
            af[t][ks] = x0 ? frag_from_f32(x0 + (size_t)lrow * 128 + (ks * 4 + q) * 8)
                           : A8[arow * 16 + ks * 4 + q];
        }
    }
    __syncthreads();

#pragma unroll
    for (int t = 0; t < 2; t++) {
        floatx4 acc[8];
#pragma unroll
        for (int ct = 0; ct < 8; ct++) acc[ct] = (floatx4){0.f, 0.f, 0.f, 0.f};
#pragma unroll
        for (int ks = 0; ks < 4; ks++) {
#pragma unroll
            for (int ct = 0; ct < 8; ct++) {
                short8 bfrag = Wl[(ct * 16 + m) * 17 + ks * 4 + q];
                acc[ct] = __builtin_amdgcn_mfma_f32_16x16x32_bf16(af[t][ks], bfrag, acc[ct], 0, 0, 0);
            }
        }

        int crow0 = (rt0 + t * 4) * 16 + q * 4;
        if (which) {
#pragma unroll
            for (int ct = 0; ct < 8; ct++) {
                int gc = ct * 16 + m;
                float bias = b2[gc];
#pragma unroll
                for (int r = 0; r < 4; r++) {
                    int gr = crow0 + r;
                    if (gr < M) Hsb[gr * 128 + gc] = f2bf(acc[ct][r] + bias);
                }
            }
        } else {
#pragma unroll
            for (int ct = 0; ct < 4; ct++) {
#pragma unroll
                for (int r = 0; r < 4; r++) {
                    int gr = crow0 + r;
                    if (gr < M)
                        XWb[gr * 64 + ct * 16 + m] = pack_bf2(acc[ct][r], acc[ct + 4][r]);
                }
            }
            float sv[4][4], dv[4][4];
#pragma unroll
            for (int h = 0; h < 4; h++) {
                float as0 = a_s[h * 32 + m], as1 = a_s[h * 32 + 16 + m];
                float ad0 = a_d[h * 32 + m], ad1 = a_d[h * 32 + 16 + m];
#pragma unroll
                for (int r = 0; r < 4; r++) {
                    sv[h][r] = acc[2 * h][r] * as0 + acc[2 * h + 1][r] * as1;
                    dv[h][r] = acc[2 * h][r] * ad0 + acc[2 * h + 1][r] * ad1;
                }
            }
#pragma unroll
            for (int off = 8; off >= 1; off >>= 1) {
#pragma unroll
                for (int h = 0; h < 4; h++)
#pragma unroll
                    for (int r = 0; r < 4; r++) {
                        sv[h][r] += __shfl_xor(sv[h][r], off);
                        dv[h][r] += __shfl_xor(dv[h][r], off);
                    }
            }
            if (m == 0) {
#pragma unroll
                for (int r = 0; r < 4; r++) {
                    int gr = crow0 + r;
                    if (gr < M) {
                        ALS4[gr] = make_float4(sv[0][r], sv[1][r], sv[2][r], sv[3][r]);
                        ALD4[gr] = make_float4(dv[0][r], dv[1][r], dv[2][r], dv[3][r]);
                    }
                }
            }
        }
    }
}

// ------- skinny MFMA GEMM + fused l2post ----------------------------------
__global__ __launch_bounds__(256) void k_gemm_small(
    const unsigned short* __restrict__ Ab,
    const unsigned short* __restrict__ WT5,
    const float* __restrict__ c2as, const float* __restrict__ c2ad,
    const float* __restrict__ l2b,
    float* __restrict__ L2D, float* __restrict__ ALD2,
    float* __restrict__ out, int M) {
    int w = threadIdx.x >> 6, lane = threadIdx.x & 63;
    int m = lane & 15, q = lane >> 4;
    const short8* A8 = (const short8*)Ab;
    const short8* W8 = (const short8*)WT5;
    floatx4 acc = (floatx4){0.f, 0.f, 0.f, 0.f};
    int arow = blockIdx.x * 64 + w * 16 + m;
#pragma unroll
    for (int ks = 0; ks < 4; ks++) {
        short8 afrag = A8[arow * 16 + ks * 4 + q];
        short8 bfrag = W8[m * 16 + ks * 4 + q];
        acc = __builtin_amdgcn_mfma_f32_16x16x32_bf16(afrag, bfrag, acc, 0, 0, 0);
    }
    float asm_ = (m < 12) ? c2as[m] : 0.f;
    float adm  = (m < 12) ? c2ad[m] : 0.f;
    int crow0 = blockIdx.x * 64 + w * 16 + q * 4;
    float sc[4], dc[4];
#pragma unroll
    for (int r = 0; r < 4; r++) {
        sc[r] = acc[r] * asm_;
        dc[r] = acc[r] * adm;
    }
#pragma unroll
    for (int r = 0; r < 4; r++) {
        sc[r] += __shfl_xor(sc[r], 1);   // lane 2h holds als[h]
        dc[r] += __shfl_xor(dc[r], 1);
    }
#pragma unroll
    for (int r = 0; r < 4; r++) {
        int gr = crow0 + r;
        if (gr >= M) continue;
        if (m < 12) {
            L2D[gr * 20 + m] = acc[r];
            if ((m & 1) == 0) {
                int h = m >> 1;
                L2D[gr * 20 + 12 + h] = sc[r];
                ALD2[gr * 8 + h] = dc[r];
            }
        } else if (m == 12) {
            out[gr * 2 + 0] = acc[r] + l2b[0];
        } else if (m == 13) {
            out[gr * 2 + 1] = acc[r] + l2b[1];
        }
    }
}

// -------- aggregation H=4,C=32 concat + skip + relu, fused exp -------------
__global__ __launch_bounds__(256) void k_agg4(
    const int* __restrict__ cntv, const unsigned short* __restrict__ col,
    const uint4* __restrict__ XWb4,
    const float4* __restrict__ ALS4, const float4* __restrict__ ALD4,
    const float* __restrict__ cb,
    const unsigned short* __restrict__ Hsb, unsigned short* __restrict__ Hb, int N) {
    int wid = threadIdx.x >> 6, lane = threadIdx.x & 63;
    int node = blockIdx.x * 4 + wid;
    if (node >= N) return;
    int deg = cntv[node];
    if (deg > CAP) deg = CAP;
    int start = node << 6;
    int gq = lane >> 4, g = lane & 15;
    int hA = g >> 3;
    int cval = col[start + lane];          // whole neighbor list, one load
    float4 cl = ((const float4*)cb)[g];
    float4 ch = ((const float4*)cb)[g + 16];
    uint2 skl = ((const uint2*)(Hsb + node * 128))[g];
    uint2 skh = ((const uint2*)(Hsb + node * 128 + 64))[g];
    float4 ad = ALD4[node];
    float adA = hA ? ad.y : ad.x;
    float adB = hA ? ad.w : ad.z;

    float a0 = 0.f, a1 = 0.f, a2 = 0.f, a3 = 0.f;
    float b0 = 0.f, b1 = 0.f, b2 = 0.f, b3 = 0.f;
    float sA = 0.f, sB = 0.f;

#define EDGE(sv)                                                       \
    {                                                                  \
        float4 as = ALS4[sv];                                          \
        uint4 u = XWb4[(size_t)(sv) * 16 + g];                         \
        float eA = __expf(leaky((hA ? as.y : as.x) + adA));            \
        float eB = __expf(leaky((hA ? as.w : as.z) + adB));            \
        sA += eA; sB += eB;                                            \
        a0 += eA * bflo(u.x); b0 += eB * bfhi(u.x);                    \
        a1 += eA * bflo(u.y); b1 += eB * bfhi(u.y);                    \
        a2 += eA * bflo(u.z); b2 += eB * bfhi(u.z);                    \
        a3 += eA * bflo(u.w); b3 += eB * bfhi(u.w);                    \
    }

    int i = 0;
    for (; i + 16 <= deg; i += 16) {   // uniform: all lanes active
        int s0 = __shfl(cval, i + gq);
        int s1 = __shfl(cval, i + 4 + gq);
        int s2 = __shfl(cval, i + 8 + gq);
        int s3 = __shfl(cval, i + 12 + gq);
        EDGE(s0) EDGE(s1) EDGE(s2) EDGE(s3)
    }
    if (i + 8 <= deg) {                // 2 edges in flight
        int s0 = __shfl(cval, i + gq);
        int s1 = __shfl(cval, i + 4 + gq);
        EDGE(s0) EDGE(s1)
        i += 8;
    }
    if (i + 4 <= deg) {
        int s0 = __shfl(cval, i + gq);
        EDGE(s0)
        i += 4;
    }
    int rem = deg - i;                  // 0..3
    if (rem > 0) {                      // wave-uniform branch
        int s0 = __shfl(cval, i + (gq < rem ? gq : 0));  // all lanes shuffle
        if (gq < rem) EDGE(s0)          // only accumulation predicated
    }
#undef EDGE

#define RED2(v) { v += __shfl_xor(v, 16); v += __shfl_xor(v, 32); }
    RED2(sA) RED2(sB)
    RED2(a0) RED2(a1) RED2(a2) RED2(a3)
    RED2(b0) RED2(b1) RED2(b2) RED2(b3)
#undef RED2

    if (gq == 0) {
        float invA = 1.f / sA, invB = 1.f / sB;
        float v0 = a0 * invA + cl.x + bflo(skl.x);
        float v1 = a1 * invA + cl.y + bfhi(skl.x);
        float v2 = a2 * invA + cl.z + bflo(skl.y);
        float v3 = a3 * invA + cl.w + bfhi(skl.y);
        float w0 = b0 * invB + ch.x + bflo(skh.x);
        float w1 = b1 * invB + ch.y + bfhi(skh.x);
        float w2 = b2 * invB + ch.z + bflo(skh.y);
        float w3 = b3 * invB + ch.w + bfhi(skh.y);
        v0 = v0 > 0.f ? v0 : 0.f;  v1 = v1 > 0.f ? v1 : 0.f;
        v2 = v2 > 0.f ? v2 : 0.f;  v3 = v3 > 0.f ? v3 : 0.f;
        w0 = w0 > 0.f ? w0 : 0.f;  w1 = w1 > 0.f ? w1 : 0.f;
        w2 = w2 > 0.f ? w2 : 0.f;  w3 = w3 > 0.f ? w3 : 0.f;
        uint2 ol, oh;
        ol.x = pack_bf2(v0, v1); ol.y = pack_bf2(v2, v3);
        oh.x = pack_bf2(w0, w1); oh.y = pack_bf2(w2, w3);
        ((uint2*)(Hb + node * 128))[g] = ol;
        ((uint2*)(Hb + node * 128 + 64))[g] = oh;
    }
}

// ---- aggregation H_LAST=6, C=2, mean, fused exp: 16 lanes per node ---------
__global__ __launch_bounds__(256) void k_agg2(
    const int* __restrict__ cntv, const unsigned short* __restrict__ col,
    const float4* __restrict__ L2D4,   // [N*5] float4 records (xw12, als6, pad2)
    const float* __restrict__ ALD2,    // [N*8]
    const float* __restrict__ c2b,
    float* __restrict__ out, int N) {
    int g = threadIdx.x >> 4, l = threadIdx.x & 15;
    int node = blockIdx.x * 16 + g;
    if (node >= N) return;
    int deg = cntv[node];
    if (deg > CAP) deg = CAP;
    int start = node << 6;

    int c0 = (l      < deg) ? (int)col[start + l]      : -1;
    int c1 = (l + 16 < deg) ? (int)col[start + l + 16] : -1;
    int c2 = (l + 32 < deg) ? (int)col[start + l + 32] : -1;
    int c3 = (l + 48 < deg) ? (int)col[start + l + 48] : -1;

    float ald[6];
    {
        float4 d03 = *(const float4*)(ALD2 + node * 8);
        float2 d45 = *(const float2*)(ALD2 + node * 8 + 4);
        ald[0] = d03.x; ald[1] = d03.y; ald[2] = d03.z; ald[3] = d03.w;
        ald[4] = d45.x; ald[5] = d45.y;
    }

    float se[6], a0[6], a1[6];
#pragma unroll
    for (int h = 0; h < 6; h++) { se[h] = 0.f; a0[h] = 0.f; a1[h] = 0.f; }

#define EDGE2(sv)                                                          \
    if ((sv) >= 0) {                                                       \
        float4 x03 = L2D4[(sv) * 5 + 0];                                   \
        float4 x47 = L2D4[(sv) * 5 + 1];                                   \
        float4 x8b = L2D4[(sv) * 5 + 2];                                   \
        float4 as03 = L2D4[(sv) * 5 + 3];                                  \
        float4 as45 = L2D4[(sv) * 5 + 4];                                  \
        float als[6] = {as03.x, as03.y, as03.z, as03.w, as45.x, as45.y};   \
        float xw[12] = {x03.x, x03.y, x03.z, x03.w, x47.x, x47.y, x47.z,   \
                        x47.w, x8b.x, x8b.y, x8b.z, x8b.w};                \
        _Pragma("unroll")                                                  \
        for (int h = 0; h < 6; h++) {                                      \
            float e = __expf(leaky(als[h] + ald[h]));                      \
            se[h] += e;                                                    \
            a0[h] += e * xw[2 * h];                                        \
            a1[h] += e * xw[2 * h + 1];                                    \
        }                                                                  \
    }

    EDGE2(c0) EDGE2(c1) EDGE2(c2) EDGE2(c3)
#undef EDGE2

#pragma unroll
    for (int m = 8; m >= 1; m >>= 1) {
#pragma unroll
        for (int h = 0; h < 6; h++) {
            se[h] += __shfl_xor(se[h], m);
            a0[h] += __shfl_xor(a0[h], m);
            a1[h] += __shfl_xor(a1[h], m);
        }
    }
    if (l == 0) {
        float o0 = 0.f, o1 = 0.f;
#pragma unroll
        for (int h = 0; h < 6; h++) {
            float inv = 1.f / se[h];
            o0 += a0[h] * inv;
            o1 += a1[h] * inv;
        }
        out[node * 2 + 0] += o0 * (1.f / 6.f) + c2b[0];
        out[node * 2 + 1] += o1 * (1.f / 6.f) + c2b[1];
    }
}

// ---------------- launch ----------------

extern "C" void kernel_launch(void* const* d_in, const int* in_sizes, int n_in,
                              void* d_out, int out_size, void* d_ws, size_t ws_size,
                              hipStream_t stream) {
    const float* x   = (const float*)d_in[0];
    const int* ei    = (const int*)d_in[1];
    // d_in[2] edge_attr: ignored
    const float* c0W = (const float*)d_in[3];
    const float* c0as = (const float*)d_in[4];
    const float* c0ad = (const float*)d_in[5];
    const float* c0b = (const float*)d_in[6];
    const float* l0W = (const float*)d_in[7];
    const float* l0b = (const float*)d_in[8];
    const float* c1W = (const float*)d_in[9];
    const float* c1as = (const float*)d_in[10];
    const float* c1ad = (const float*)d_in[11];
    const float* c1b = (const float*)d_in[12];
    const float* l1W = (const float*)d_in[13];
    const float* l1b = (const float*)d_in[14];
    const float* c2W = (const float*)d_in[15];
    const float* c2as = (const float*)d_in[16];
    const float* c2ad = (const float*)d_in[17];
    const float* c2b = (const float*)d_in[18];
    const float* l2W = (const float*)d_in[19];
    const float* l2b = (const float*)d_in[20];
    float* out = (float*)d_out;

    const int N = in_sizes[0] / 128;
    const int E = in_sizes[1] / 2;
    const int ET = E + N;
    const int Mpad = (N + 63) & ~63;

    // workspace carve (256B aligned)
    char* p = (char*)d_ws;
    auto alloc = [&](size_t bytes) -> void* {
        void* r = (void*)p;
        p += (bytes + 255) & ~(size_t)255;
        return r;
    };
    unsigned short* Hsb = (unsigned short*)alloc((size_t)N * 128 * 2);  // bf16 skip
    unsigned int* XWb = (unsigned int*)alloc((size_t)N * 64 * 4);       // packed bf16 pairs
    unsigned short* Ab = (unsigned short*)alloc((size_t)Mpad * 128 * 2);
    unsigned short* W1T = (unsigned short*)alloc(128 * 128 * 2);
    unsigned short* W2T = (unsigned short*)alloc(128 * 128 * 2);
    unsigned short* W3T = (unsigned short*)alloc(128 * 128 * 2);
    unsigned short* W4T = (unsigned short*)alloc(128 * 128 * 2);
    unsigned short* WT5 = (unsigned short*)alloc(16 * 128 * 2);
    float* ALS = (float*)alloc((size_t)N * 4 * 4);     // [N][4] layers 0/1
    float* ALD = (float*)alloc((size_t)N * 8 * 4);     // [N][4] L0/L1; [N][8] L2
    float* L2D = (float*)alloc((size_t)N * 20 * 4);    // layer-2 node records
    int* cnt    = (int*)alloc((size_t)N * 4);
    unsigned short* col = (unsigned short*)alloc((size_t)N * CAP * 2);  // buckets

    // --- bucket build + weight converts (one kernel) ---
    hipMemsetAsync(cnt, 0, (size_t)N * 4, stream);
    int rs = (N + 7) / 8;
    int chunks = (ET + SC_CHUNK - 1) / SC_CHUNK;
    dim3 bgrid(8, chunks + 1);
    k_bucket<<<bgrid, 256, 0, stream>>>(ei, E, N, rs, cnt, col,
                                        c0W, W1T, l0W, W2T, c1W, W3T, l1W, W4T,
                                        c2W, l2W, WT5);

    // 128 rows per block (2 tiles/wave)
    dim3 ggrid((Mpad + 127) / 128, 2);
    int nwb = (N + 3) / 4;  // wave-per-node blocks

    // --- layer 0 (GEMM reads x fp32 directly) ---
    k_gemm_mfma<<<ggrid, 256, 0, stream>>>(x, Ab, W1T, XWb, c0as, c0ad,
                                           (float4*)ALS, (float4*)ALD,
                                           W2T, l0b, Hsb, N);
    k_agg4<<<nwb, 256, 0, stream>>>(cnt, col, (const uint4*)XWb,
                                    (const float4*)ALS, (const float4*)ALD,
                                    c0b, Hsb, Ab, N);

    // --- layer 1 --- (Ab holds bf16(H0); pad rows masked in epilogues)
    k_gemm_mfma<<<ggrid, 256, 0, stream>>>(nullptr, Ab, W3T, XWb, c1as, c1ad,
                                           (float4*)ALS, (float4*)ALD,
                                           W4T, l1b, Hsb, N);
    k_agg4<<<nwb, 256, 0, stream>>>(cnt, col, (const uint4*)XWb,
                                    (const float4*)ALS, (const float4*)ALD,
                                    c1b, Hsb, Ab, N);

    // --- layer 2 --- (Ab holds bf16(H1)); gemm_small has fused l2post
    k_gemm_small<<<Mpad / 64, 256, 0, stream>>>(Ab, WT5, c2as, c2ad, l2b,
                                                L2D, ALD, out, N);
    k_agg2<<<(N + 15) / 16, 256, 0, stream>>>(cnt, col, (const float4*)L2D,
                                              ALD, c2b, out, N);
}